// Round 9
// baseline (264.391 us; speedup 1.0000x reference)
//
#include <hip/hip_runtime.h>
#include <hip/hip_bf16.h>

// ============================================================================
// Round 9: (a) conv MFMA body generalized to ROWS-per-wave, 256-thr/4-wave
// blocks: conv4 ROWS=4 -> 16 ds_reads per 48 MFMAs (1.5x less LDS/MFMA,
// LDS 15us < MFMA 28us floor), 3 blocks/CU; conv1/conv3 ROWS=2 8x16 tiles ->
// grid 512, 2-3 blocks/CU (was 1). (b) launch count 16 -> 9: wprep x3 -> 1,
// halo x2 -> 1, pool+enc fused (t2 eliminated), lstm+gamma+rowsum fused,
// ntmout+conv2 fused. All arithmetic bit-identical to r8 (floor 3.814697e-6).
// ============================================================================

typedef __attribute__((ext_vector_type(8))) short short8;
typedef __attribute__((ext_vector_type(4))) float f32x4;

// ---- workspace layout (bytes) ----
static const size_t OFF_A1H = 0;                       // A1/A4 NHWC hi (B,34,34,64)
static const size_t OFF_A1L = 9469952;                 // -> end 18,939,904
static const size_t OFF_T1  = 18939904;                // t1 conv1 out NCHW f32 16MB
static const size_t OFF_A3H = 39911424;                // conv3 input NHWC (B,18,18,64)
static const size_t OFF_A3L = 42565632;                // -> end 45,219,840
static const size_t OFF_W1  = 45219840;                // packed whi+wlo 147,456 B/layer
static const size_t OFF_W3  = 45367296;
static const size_t OFF_W4  = 45514752;
static const size_t OFF_XE  = 45662208;                // xE (64,256) f32
static const size_t OFF_H   = 45727744;                // h  (64,256) f32
static const size_t OFF_RV  = 45793280;                // rv (64,3) f64
static const size_t OFF_RS  = 45794816;                // rs (3,256) f64

__device__ inline void bf16split(float v, unsigned short& h, unsigned short& l) {
    __hip_bfloat16 hb = __float2bfloat16(v);
    float hf = __bfloat162float(hb);
    __hip_bfloat16 lb = __float2bfloat16(v - hf);
    h = __builtin_bit_cast(unsigned short, hb);
    l = __builtin_bit_cast(unsigned short, lb);
}

// ---- weight prep, all 3 layers: (co,ci,3,3) f32 -> fragment-packed hi/lo ----
// pack idx r = (((t*2+ch)*4+n)*64 + lane)*8 + j ; lane=(kg<<4)|lc
// co = n*16+lc ; ci = ch*32 + kg*8 + j ; value = w[(co*64+ci)*9 + t]
__global__ void wprep_all_kernel(
    const float* __restrict__ w1, const float* __restrict__ w3,
    const float* __restrict__ w4,
    unsigned short* __restrict__ whi1, unsigned short* __restrict__ wlo1,
    unsigned short* __restrict__ whi3, unsigned short* __restrict__ wlo3,
    unsigned short* __restrict__ whi4, unsigned short* __restrict__ wlo4)
{
    int layer = blockIdx.x / 144;                      // 144 blocks per layer
    int r = (blockIdx.x % 144) * 256 + threadIdx.x;    // < 36864
    const float* w = layer == 0 ? w1 : (layer == 1 ? w3 : w4);
    unsigned short* hi = layer == 0 ? whi1 : (layer == 1 ? whi3 : whi4);
    unsigned short* lo = layer == 0 ? wlo1 : (layer == 1 ? wlo3 : wlo4);
    int j  = r & 7;
    int ln = (r >> 3) & 63;
    int n  = (r >> 9) & 3;
    int ch = (r >> 11) & 1;
    int t  = r >> 12;
    int lc = ln & 15, kg = ln >> 4;
    int co = n * 16 + lc;
    int ci = ch * 32 + kg * 8 + j;
    unsigned short h, l;
    bf16split(w[(co * 64 + ci) * 9 + t], h, l);
    hi[r] = h; lo[r] = l;
}

// ---- zero halo rings of a1 (S=32) and a3 (S=16) in one kernel ----
__device__ inline void halo_zero_one(unsigned short* hi, unsigned short* lo,
                                     int S, int idx)
{
    int P = S + 2, ring = 4 * S + 4;
    int co = idx & 63;
    int cell = (idx >> 6) % ring;
    int b = (idx >> 6) / ring;
    int y, x;
    if (cell < P)            { y = 0;     x = cell; }
    else if (cell < 2 * P)   { y = P - 1; x = cell - P; }
    else { int c2 = cell - 2 * P; y = 1 + (c2 >> 1); x = (c2 & 1) ? P - 1 : 0; }
    size_t a = ((size_t)(b * P + y) * P + x) * 64 + co;
    hi[a] = 0; lo[a] = 0;
}

__global__ void halo_all_kernel(unsigned short* __restrict__ a1h,
                                unsigned short* __restrict__ a1l,
                                unsigned short* __restrict__ a3h,
                                unsigned short* __restrict__ a3l)
{
    int idx = blockIdx.x * 256 + threadIdx.x;          // 819,200 total
    if (idx < 540672) halo_zero_one(a1h, a1l, 32, idx);
    else              halo_zero_one(a3h, a3l, 16, idx - 540672);
}

// ---- fused conv0 (1->64, 3x3 SAME, relu) + avgpool2 -> A1 NHWC hi/lo ----
__global__ __launch_bounds__(256) void conv0_pool_kernel(
    const float* __restrict__ in, const float* __restrict__ w,
    const float* __restrict__ bias,
    unsigned short* __restrict__ ohi, unsigned short* __restrict__ olo)
{
    int idx = blockIdx.x * 256 + threadIdx.x;          // 4,194,304
    int co = idx & 63, x = (idx >> 6) & 31, y = (idx >> 11) & 31, b = idx >> 16;
    float w9[9];
#pragma unroll
    for (int t = 0; t < 9; ++t) w9[t] = w[co * 9 + t];
    float bv = bias[co];
    const float* ip = in + (size_t)b * 4096;
    float p[4][4];
#pragma unroll
    for (int r = 0; r < 4; ++r) {
        int gy = 2 * y - 1 + r;
#pragma unroll
        for (int c = 0; c < 4; ++c) {
            int gx = 2 * x - 1 + c;
            float v = 0.f;
            if ((unsigned)gy < 64u && (unsigned)gx < 64u) v = ip[gy * 64 + gx];
            p[r][c] = v;
        }
    }
    float s4 = 0.f;
#pragma unroll
    for (int dy = 0; dy < 2; ++dy)
#pragma unroll
        for (int dx = 0; dx < 2; ++dx) {
            float a = bv;
#pragma unroll
            for (int ky = 0; ky < 3; ++ky)
#pragma unroll
                for (int kx = 0; kx < 3; ++kx)
                    a = fmaf(w9[ky * 3 + kx], p[dy + ky][dx + kx], a);
            s4 += fmaxf(a, 0.f);
        }
    unsigned short h, l;
    bf16split(s4 * 0.25f, h, l);
    size_t a = ((size_t)(b * 34 + y + 1) * 34 + x + 1) * 64 + co;
    ohi[a] = h; olo[a] = l;
}

// ---- MFMA implicit-GEMM conv body: 256 thr / 4 waves, ROWS rows per wave ----
// Tile: (4*ROWS) x 16 outputs. A in LDS (XOR swizzle), B slice dbuf in LDS.
template <int UP, int H, int ROWS, bool NHWC_OUT>
__device__ __forceinline__ void conv_mfma_body(
    const unsigned short* __restrict__ ahi, const unsigned short* __restrict__ alo,
    const unsigned short* __restrict__ whiP, const unsigned short* __restrict__ wloP,
    const float* __restrict__ bias,
    float* __restrict__ outf, unsigned short* __restrict__ ohi,
    unsigned short* __restrict__ olo)
{
    constexpr int TILEH = 4 * ROWS;
    constexpr int SRC   = H >> UP;
    constexpr int PITCH = SRC + 2;
    constexpr int TPR   = H / 16;
    constexpr int TPC   = H / TILEH;
    constexpr int AH    = (UP ? TILEH / 2 : TILEH) + 2;
    constexpr int AW    = UP ? 10 : 18;
    constexpr int NPX   = AH * AW;

    int b  = blockIdx.x / (TPC * TPR);
    int tt = blockIdx.x % (TPC * TPR);
    int y0 = (tt / TPR) * TILEH, x0 = (tt % TPR) * 16;
    const int tid = threadIdx.x;
    const int wv = tid >> 6, lane = tid & 63;
    const int lc = lane & 15, kg = lane >> 4;

    __shared__ unsigned short sAhi[NPX * 64];
    __shared__ unsigned short sAlo[NPX * 64];
    __shared__ unsigned short sW[2][4096];             // [buf][hi 2048 | lo 2048]

    const int r0 = ((y0 - 1) >> UP) + 1;
    const int c0 = ((x0 - 1) >> UP) + 1;

    // stage A: coalesced 16B chunks, XOR-swizzled destination
    for (int c = tid; c < NPX * 8; c += 256) {
        int pix = c >> 3, sub = c & 7;
        int py = pix / AW, px = pix - py * AW;
        size_t g = ((size_t)(b * PITCH + r0 + py) * PITCH + (c0 + px)) * 64 + sub * 8;
        int l = (pix * 64 + sub * 8) ^ ((pix & 7) << 3);
        *(short8*)&sAhi[l] = *(const short8*)&ahi[g];
        *(short8*)&sAlo[l] = *(const short8*)&alo[g];
    }
    // stage W slice k=0
    for (int c = tid; c < 512; c += 256) {
        if (c < 256) *(short8*)&sW[0][c * 8] = *(const short8*)&whiP[c * 8];
        else *(short8*)&sW[0][2048 + (c - 256) * 8] = *(const short8*)&wloP[(c - 256) * 8];
    }
    __syncthreads();

    int lxv[3], lyv[ROWS + 2];
#pragma unroll
    for (int kx = 0; kx < 3; ++kx)
        lxv[kx] = (((x0 + lc + kx - 1) >> UP) + 1) - c0;
#pragma unroll
    for (int r = 0; r < ROWS + 2; ++r)
        lyv[r] = (((y0 + ROWS * wv + r - 1) >> UP) + 1) - r0;

    f32x4 acc[ROWS][4];
#pragma unroll
    for (int m = 0; m < ROWS; ++m)
#pragma unroll
        for (int n = 0; n < 4; ++n) acc[m][n] = f32x4{0.f, 0.f, 0.f, 0.f};

#pragma unroll
    for (int k = 0; k < 18; ++k) {                     // k = t*2 + ch
        if (k + 1 < 18) {                              // prefetch next W slice
            int slb = (k + 1) * 2048;
            for (int c = tid; c < 512; c += 256) {
                if (c < 256) *(short8*)&sW[(k + 1) & 1][c * 8] =
                    *(const short8*)&whiP[slb + c * 8];
                else *(short8*)&sW[(k + 1) & 1][2048 + (c - 256) * 8] =
                    *(const short8*)&wloP[slb + (c - 256) * 8];
            }
        }
        const int t = k >> 1, ch = k & 1;
        const int ky = t / 3, kx = t - ky * 3;
        short8 ah[ROWS], al[ROWS];
#pragma unroll
        for (int m = 0; m < ROWS; ++m) {
            int p = lyv[ky + m] * AW + lxv[kx];
            int i = (p * 64 + ch * 32 + kg * 8) ^ ((p & 7) << 3);
            ah[m] = *(const short8*)&sAhi[i];
            al[m] = *(const short8*)&sAlo[i];
        }
        const unsigned short* wb = &sW[k & 1][0];
#pragma unroll
        for (int n = 0; n < 4; ++n) {
            short8 bh = *(const short8*)&wb[(n * 64 + lane) * 8];
            short8 bl = *(const short8*)&wb[2048 + (n * 64 + lane) * 8];
#pragma unroll
            for (int m = 0; m < ROWS; ++m) {
                acc[m][n] = __builtin_amdgcn_mfma_f32_16x16x32_bf16(ah[m], bh, acc[m][n], 0, 0, 0);
                acc[m][n] = __builtin_amdgcn_mfma_f32_16x16x32_bf16(ah[m], bl, acc[m][n], 0, 0, 0);
                acc[m][n] = __builtin_amdgcn_mfma_f32_16x16x32_bf16(al[m], bh, acc[m][n], 0, 0, 0);
            }
        }
        __syncthreads();
    }

    // epilogue: D col(lane&15)=co frag idx, row(kg*4+reg)=pixel-x (verified r4)
    if (NHWC_OUT) {
        const int opitch = H + 2;
#pragma unroll
        for (int n = 0; n < 4; ++n) {
            int co = n * 16 + lc;
            float bv = bias[co];
#pragma unroll
            for (int m = 0; m < ROWS; ++m) {
                int row = y0 + ROWS * wv + m, cb = x0 + kg * 4;
                f32x4 v = acc[m][n];
#pragma unroll
                for (int j = 0; j < 4; ++j) {
                    float val = fmaxf(v[j] + bv, 0.f);
                    unsigned short h, l;
                    bf16split(val, h, l);
                    size_t a = ((size_t)(b * opitch + row + 1) * opitch + cb + j + 1) * 64 + co;
                    ohi[a] = h; olo[a] = l;
                }
            }
        }
    } else {
#pragma unroll
        for (int n = 0; n < 4; ++n) {
            int co = n * 16 + lc;
            float bv = bias[co];
#pragma unroll
            for (int m = 0; m < ROWS; ++m) {
                int row = y0 + ROWS * wv + m, cb = x0 + kg * 4;
                f32x4 v = acc[m][n], res;
                res.x = fmaxf(v.x + bv, 0.f);
                res.y = fmaxf(v.y + bv, 0.f);
                res.z = fmaxf(v.z + bv, 0.f);
                res.w = fmaxf(v.w + bv, 0.f);
                *(f32x4*)&outf[((size_t)(b * 64 + co) * H + row) * H + cb] = res;
            }
        }
    }
}

__global__ __launch_bounds__(256, 2) void conv1_mfma_kernel(
    const unsigned short* __restrict__ ahi, const unsigned short* __restrict__ alo,
    const unsigned short* __restrict__ whiP, const unsigned short* __restrict__ wloP,
    const float* __restrict__ bias, float* __restrict__ outf)
{ conv_mfma_body<0, 32, 2, false>(ahi, alo, whiP, wloP, bias, outf, nullptr, nullptr); }

__global__ __launch_bounds__(256, 3) void conv3_mfma_kernel(
    const unsigned short* __restrict__ ahi, const unsigned short* __restrict__ alo,
    const unsigned short* __restrict__ whiP, const unsigned short* __restrict__ wloP,
    const float* __restrict__ bias,
    unsigned short* __restrict__ ohi, unsigned short* __restrict__ olo)
{ conv_mfma_body<1, 32, 2, true>(ahi, alo, whiP, wloP, bias, nullptr, ohi, olo); }

__global__ __launch_bounds__(256, 3) void conv4_mfma_kernel(
    const unsigned short* __restrict__ ahi, const unsigned short* __restrict__ alo,
    const unsigned short* __restrict__ whiP, const unsigned short* __restrict__ wloP,
    const float* __restrict__ bias, float* __restrict__ outf)
{ conv_mfma_body<1, 64, 4, false>(ahi, alo, whiP, wloP, bias, outf, nullptr, nullptr); }

// ---- fused avgpool2 + enc conv: t1 (64,64,32,32) -> xE (64,256) ----
__global__ __launch_bounds__(256) void pool_enc_kernel(
    const float* __restrict__ t1, const float* __restrict__ w,
    const float* __restrict__ bias, float* __restrict__ xout)
{
    int b = blockIdx.x; int tid = threadIdx.x;
    __shared__ float sE[16384];                        // pooled (64,16,16)
    for (int p = tid; p < 16384; p += 256) {
        int ch = p >> 8, y = (p >> 4) & 15, x = p & 15;
        const float* ip = t1 + ((size_t)(b * 64 + ch) * 32 + 2 * y) * 32 + 2 * x;
        sE[p] = (ip[0] + ip[1] + ip[32] + ip[33]) * 0.25f;
    }
    __syncthreads();
    int y = tid >> 4, x = tid & 15;
    double acc = 0.0;
    for (int ci = 0; ci < 64; ++ci) {
#pragma unroll
        for (int ky = 0; ky < 3; ++ky) {
            int gy = y + ky - 1;
            if ((unsigned)gy >= 16u) continue;
#pragma unroll
            for (int kx = 0; kx < 3; ++kx) {
                int gx = x + kx - 1;
                if ((unsigned)gx >= 16u) continue;
                acc = fma((double)w[ci * 9 + ky * 3 + kx],
                          (double)sE[ci * 256 + gy * 16 + gx], acc);
            }
        }
    }
    float v = (float)(acc + (double)bias[0]);
    xout[b * 256 + tid] = fmaxf(v, 0.f);
}

// ---- fused LSTM + gamma (blocks 0..63) and rowsum (blocks 64..66) ----
__global__ __launch_bounds__(256) void lstm_gamma_rowsum_kernel(
    const float* __restrict__ x, const float* __restrict__ wx,
    const float* __restrict__ bl, const float* __restrict__ w_param,
    const float* __restrict__ b_param, const float* __restrict__ w_out,
    float* __restrict__ h, double* __restrict__ rv, double* __restrict__ rs)
{
    int blk = blockIdx.x;
    int tid = threadIdx.x;
    if (blk >= 64) {                                   // rowsum, r = blk-64
        int r = blk - 64, m = tid;
        double s = 0;
        for (int d = 0; d < 256; ++d)
            s += (double)w_out[(size_t)(256 + r * 256 + d) * 256 + m];
        rs[r * 256 + m] = s;
        return;
    }
    int b = blk, j = tid;
    __shared__ float sx[256];
    __shared__ float sh[256];
    __shared__ double sp[3][256];
    sx[j] = x[b * 256 + j];
    __syncthreads();
    double zi = 0, zg = 0, zo = 0;
    for (int d = 0; d < 256; ++d) {
        double xv = (double)sx[d];
        const float* row = wx + (size_t)d * 1024;
        zi = fma(xv, (double)row[j], zi);
        zg = fma(xv, (double)row[512 + j], zg);
        zo = fma(xv, (double)row[768 + j], zo);
    }
    float zif = (float)(zi + (double)bl[j]);
    float zgf = (float)(zg + (double)bl[512 + j]);
    float zof = (float)(zo + (double)bl[768 + j]);
    double c = (1.0 / (1.0 + exp(-(double)zif))) * tanh((double)zgf);
    float cf = (float)c;
    double hh = (1.0 / (1.0 + exp(-(double)zof))) * tanh((double)cf);
    float hv = (float)hh;
    sh[j] = hv;
    h[b * 256 + j] = hv;
    __syncthreads();
    // gamma part (bit-identical to r8 gamma_kernel)
#pragma unroll
    for (int r = 0; r < 3; ++r)
        sp[r][j] = (double)sh[j] * (double)w_param[(size_t)j * 3108 + r * 262 + 261];
    __syncthreads();
    if (j < 3) {
        double s = 0;
        for (int d = 0; d < 256; ++d) s += sp[j][d];
        float pf = (float)(s + (double)b_param[j * 262 + 261]);
        pf = fminf(fmaxf(pf, -20.f), 20.f);
        double gamma = log1p(exp((double)pf)) + 1.0;
        double q = pow(0.015625 + 1e-16, gamma);
        double wv = q / (64.0 * q + 1e-8);
        rv[b * 3 + j] = wv * 64.0 * 1e-6;
    }
}

// ---- fused ntm-out + conv2 -> A3 NHWC hi/lo (block b = one image) ----
__global__ __launch_bounds__(256) void ntmout_conv2_kernel(
    const float* __restrict__ h, const float* __restrict__ w_out,
    const float* __restrict__ b_out, const double* __restrict__ rv,
    const double* __restrict__ rs, const float* __restrict__ w2,
    const float* __restrict__ b2,
    unsigned short* __restrict__ ohi, unsigned short* __restrict__ olo)
{
    int b = blockIdx.x, m = threadIdx.x;
    __shared__ float sh[256];
    __shared__ double srv[3];
    __shared__ float sNtm[256];
    sh[m] = h[b * 256 + m];
    if (m < 3) srv[m] = rv[b * 3 + m];
    __syncthreads();
    double acc = 0;
    for (int d = 0; d < 256; ++d)
        acc = fma((double)sh[d], (double)w_out[(size_t)d * 256 + m], acc);
    acc += (double)b_out[m];
#pragma unroll
    for (int r = 0; r < 3; ++r) acc += srv[r] * rs[r * 256 + m];
    acc = fmin(fmax(acc, -20.0), 20.0);
    sNtm[m] = (float)acc;                              // ntm[b] = 16x16 image
    __syncthreads();
    // conv2: 1->64 3x3 SAME + relu, output (y,x,co) with co innermost
    for (int p = m; p < 16384; p += 256) {
        int co = p & 63, x4 = (p >> 6) & 15, y4 = p >> 10;
        float a = b2[co];
#pragma unroll
        for (int ky = 0; ky < 3; ++ky) {
            int gy = y4 + ky - 1;
            if ((unsigned)gy >= 16u) continue;
#pragma unroll
            for (int kx = 0; kx < 3; ++kx) {
                int gx = x4 + kx - 1;
                if ((unsigned)gx >= 16u) continue;
                a = fmaf(w2[co * 9 + ky * 3 + kx], sNtm[gy * 16 + gx], a);
            }
        }
        unsigned short hh, ll;
        bf16split(fmaxf(a, 0.f), hh, ll);
        size_t adst = ((size_t)(b * 18 + y4 + 1) * 18 + x4 + 1) * 64 + co;
        ohi[adst] = hh; olo[adst] = ll;
    }
}

extern "C" void kernel_launch(void* const* d_in, const int* in_sizes, int n_in,
                              void* d_out, int out_size, void* d_ws, size_t ws_size,
                              hipStream_t stream)
{
    const float* inputs   = (const float*)d_in[0];
    const float* w_conv0  = (const float*)d_in[1];
    const float* b_conv0  = (const float*)d_in[2];
    const float* w_conv1  = (const float*)d_in[3];
    const float* b_conv1  = (const float*)d_in[4];
    const float* w_enc    = (const float*)d_in[5];
    const float* b_enc    = (const float*)d_in[6];
    const float* w_conv2  = (const float*)d_in[7];
    const float* b_conv2  = (const float*)d_in[8];
    const float* w_conv3  = (const float*)d_in[9];
    const float* b_conv3  = (const float*)d_in[10];
    const float* w_conv4  = (const float*)d_in[11];
    const float* b_conv4  = (const float*)d_in[12];
    const float* w_lstm_x = (const float*)d_in[13];
    // d_in[14] = w_lstm_h : dead (h0 == 0)
    const float* b_lstm   = (const float*)d_in[15];
    const float* w_param  = (const float*)d_in[16];
    const float* b_param  = (const float*)d_in[17];
    const float* w_out_   = (const float*)d_in[18];
    const float* b_out_   = (const float*)d_in[19];

    char* ws = (char*)d_ws;
    unsigned short* a1h = (unsigned short*)(ws + OFF_A1H);
    unsigned short* a1l = (unsigned short*)(ws + OFF_A1L);
    float*  t1  = (float*)(ws + OFF_T1);
    unsigned short* a3h = (unsigned short*)(ws + OFF_A3H);
    unsigned short* a3l = (unsigned short*)(ws + OFF_A3L);
    unsigned short* a4h = a1h;                         // A4 reuses A1
    unsigned short* a4l = a1l;
    unsigned short* whi1 = (unsigned short*)(ws + OFF_W1); unsigned short* wlo1 = whi1 + 36864;
    unsigned short* whi3 = (unsigned short*)(ws + OFF_W3); unsigned short* wlo3 = whi3 + 36864;
    unsigned short* whi4 = (unsigned short*)(ws + OFF_W4); unsigned short* wlo4 = whi4 + 36864;
    float*  xE  = (float*)(ws + OFF_XE);
    float*  h   = (float*)(ws + OFF_H);
    double* rv  = (double*)(ws + OFF_RV);
    double* rs  = (double*)(ws + OFF_RS);

    wprep_all_kernel<<<432, 256, 0, stream>>>(w_conv1, w_conv3, w_conv4,
                                              whi1, wlo1, whi3, wlo3, whi4, wlo4);
    halo_all_kernel<<<3200, 256, 0, stream>>>(a1h, a1l, a3h, a3l);

    conv0_pool_kernel<<<16384, 256, 0, stream>>>(inputs, w_conv0, b_conv0, a1h, a1l);
    conv1_mfma_kernel<<<512, 256, 0, stream>>>(a1h, a1l, whi1, wlo1, b_conv1, t1);
    pool_enc_kernel<<<64, 256, 0, stream>>>(t1, w_enc, b_enc, xE);

    lstm_gamma_rowsum_kernel<<<67, 256, 0, stream>>>(
        xE, w_lstm_x, b_lstm, w_param, b_param, w_out_, h, rv, rs);
    ntmout_conv2_kernel<<<64, 256, 0, stream>>>(
        h, w_out_, b_out_, rv, rs, w_conv2, b_conv2, a3h, a3l);

    conv3_mfma_kernel<<<512, 256, 0, stream>>>(a3h, a3l, whi3, wlo3, b_conv3, a4h, a4l);
    conv4_mfma_kernel<<<1024, 256, 0, stream>>>(a4h, a4l, whi4, wlo4, b_conv4, (float*)d_out);
}